// Round 6
// baseline (151.914 us; speedup 1.0000x reference)
//
#include <hip/hip_runtime.h>

// Problem: A=8, B=16, N=M=1024, K=64. u:(A,B,N,K) f32, v:(A,B,M,K) f32.
// out0 = u * (dot(u_row, v_sum) > 0), out1 = v * (dot(v_row, u_sum) > 0)
//
// Round-9: ONE BLOCK PER BATCH (128 blocks x 1024 threads). History:
//   R1 (256 blk, half-batch, dup reads, 2 barriers)   : 28.8 us   <- best
//   R3 (pairwise ws exchange, read-once)              : 30.7
//   R4 (two-kernel L3 split)                          : 32.8
//   R5 (3-act R/W overlap schedule)                   : 32.5
// All schedule tricks lose to R1's plain burst-read -> reduce -> burst-write.
// Model: R1 is HBM-bound at its ACTUAL fetch: duplicates only partially
// L2-absorbed (~110 MB effective fetch -> 177 MB HBM -> 28.1 us at 6.3 TB/s
// ~= measured 28.8). The only zero-sync way to fetch 67 MB exactly is one
// block per batch: whole batch -> registers (ur[16]+vr[16] = 128 VGPR/thread,
// fits 4 waves/SIMD at <=512), ONE barrier (both colsums reduced in the same
// phase), mask from regs, NT-store. Same 32-load up-front burst as R1 -> MLP
// preserved. Risk: only 128 CUs active; if they can't saturate HBM this
// regresses and R1 was the roofline.

#define NBATCH 128        // A*B
#define NROW   1024       // N == M
#define KDIM   64
#define ELEMS_PER_TENSOR (128ull * 1024ull * 64ull)  // 8388608

typedef float floatx4 __attribute__((ext_vector_type(4)));  // for nontemporal builtin

__global__ __launch_bounds__(1024)
void fused_batch_kernel(const float* __restrict__ u,
                        const float* __restrict__ v,
                        float* __restrict__ out) {
    const int batch = blockIdx.x;        // 0..127; round-robin -> 16 blocks/XCD
    const int tid   = threadIdx.x;       // 0..1023
    const int k4    = tid & 15;          // float4 column group (16 x 4 = 64 cols)
    const int rg    = tid >> 4;          // 0..63 row group
    const int wave  = tid >> 6;          // 0..15

    const size_t boff = (size_t)batch * NROW * KDIM;
    const float4* ub = (const float4*)(u + boff);
    const float4* vb = (const float4*)(v + boff);
    float* ou = out + boff;
    float* ov = out + ELEMS_PER_TENSOR + boff;

    // ---- Phase A: read the WHOLE batch once -> registers + colsum partials -
    // Thread covers rows {rg + 64*i}, i=0..15; wave = 4 rows x 1KB, coalesced.
    float4 ur[16], vr[16];
    float4 su = make_float4(0.f, 0.f, 0.f, 0.f);
    float4 sv = make_float4(0.f, 0.f, 0.f, 0.f);
    #pragma unroll
    for (int i = 0; i < 16; ++i) {
        size_t io = (size_t)(rg + 64 * i) * 16 + k4;
        ur[i] = ub[io];
        vr[i] = vb[io];
    }
    #pragma unroll
    for (int i = 0; i < 16; ++i) {
        su.x += ur[i].x; su.y += ur[i].y; su.z += ur[i].z; su.w += ur[i].w;
        sv.x += vr[i].x; sv.y += vr[i].y; sv.z += vr[i].z; sv.w += vr[i].w;
    }

    // ---- Reduce: shfl across the 4 row-groups within each wave ------------
    su.x += __shfl_xor(su.x, 16); su.y += __shfl_xor(su.y, 16);
    su.z += __shfl_xor(su.z, 16); su.w += __shfl_xor(su.w, 16);
    su.x += __shfl_xor(su.x, 32); su.y += __shfl_xor(su.y, 32);
    su.z += __shfl_xor(su.z, 32); su.w += __shfl_xor(su.w, 32);
    sv.x += __shfl_xor(sv.x, 16); sv.y += __shfl_xor(sv.y, 16);
    sv.z += __shfl_xor(sv.z, 16); sv.w += __shfl_xor(sv.w, 16);
    sv.x += __shfl_xor(sv.x, 32); sv.y += __shfl_xor(sv.y, 32);
    sv.z += __shfl_xor(sv.z, 32); sv.w += __shfl_xor(sv.w, 32);

    __shared__ float4 red_u[16][16];   // [wave][k4]
    __shared__ float4 red_v[16][16];
    if ((tid & 63) < 16) {             // lanes 0..15 hold k4 = lane
        red_u[wave][k4] = su;
        red_v[wave][k4] = sv;
    }
    __syncthreads();                   // the ONLY barrier

    // all-thread self-reduce; same-k4 threads read same address (broadcast)
    float4 us = make_float4(0.f, 0.f, 0.f, 0.f);  // u colsum (masks v rows)
    float4 vs = make_float4(0.f, 0.f, 0.f, 0.f);  // v colsum (masks u rows)
    #pragma unroll
    for (int w = 0; w < 16; ++w) {
        float4 a = red_u[w][k4];
        float4 b = red_v[w][k4];
        us.x += a.x; us.y += a.y; us.z += a.z; us.w += a.w;
        vs.x += b.x; vs.y += b.y; vs.z += b.z; vs.w += b.w;
    }

    // ---- Phase B: mask from registers, streaming NT stores ----------------
    #pragma unroll
    for (int i = 0; i < 16; ++i) {
        size_t io = (size_t)(rg + 64 * i) * 16 + k4;

        float pu = ur[i].x * vs.x + ur[i].y * vs.y + ur[i].z * vs.z + ur[i].w * vs.w;
        pu += __shfl_xor(pu, 1);
        pu += __shfl_xor(pu, 2);
        pu += __shfl_xor(pu, 4);
        pu += __shfl_xor(pu, 8);       // full 64-col dot across the 16 k4 lanes
        float mu = (pu > 0.f) ? 1.f : 0.f;
        floatx4 outu = { ur[i].x * mu, ur[i].y * mu, ur[i].z * mu, ur[i].w * mu };
        __builtin_nontemporal_store(outu, (floatx4*)(ou + io * 4));

        float pv = vr[i].x * us.x + vr[i].y * us.y + vr[i].z * us.z + vr[i].w * us.w;
        pv += __shfl_xor(pv, 1);
        pv += __shfl_xor(pv, 2);
        pv += __shfl_xor(pv, 4);
        pv += __shfl_xor(pv, 8);
        float mv = (pv > 0.f) ? 1.f : 0.f;
        floatx4 outv = { vr[i].x * mv, vr[i].y * mv, vr[i].z * mv, vr[i].w * mv };
        __builtin_nontemporal_store(outv, (floatx4*)(ov + io * 4));
    }
}

extern "C" void kernel_launch(void* const* d_in, const int* in_sizes, int n_in,
                              void* d_out, int out_size, void* d_ws, size_t ws_size,
                              hipStream_t stream) {
    const float* u = (const float*)d_in[0];
    const float* v = (const float*)d_in[1];
    float* out = (float*)d_out;

    fused_batch_kernel<<<dim3(128), dim3(1024), 0, stream>>>(u, v, out);
}

// Round 8
// 149.380 us; speedup vs baseline: 1.0170x; 1.0170x over previous
//
#include <hip/hip_runtime.h>

// Problem: A=8, B=16, N=M=1024, K=64. u:(A,B,N,K) f32, v:(A,B,M,K) f32.
// out0 = u * (dot(u_row, v_sum) > 0), out1 = v * (dot(v_row, u_sum) > 0)
//
// Round-11: RESUBMIT of round-10 (same-order pair traversal). Round-10's
// bench died with "container failed twice" — but this kernel has no
// container-killing mechanism (plain launch, no coop, no atomics, no spin,
// uniform branches, same addressing as the healthy R1 kernel). Session infra
// was visibly flaky (acquire 5..102 s, one 882 s npz push). Per rigor
// discipline: don't change two variables at once — re-measure the SAME
// hypothesis.
//
// Scoreboard: R1 (pair swizzle, own-first order) 28.8 us; R3 exchange 30.7;
// R4 split 32.8; R5 acts 32.5; R6 one-block-per-batch 67.4 (VGPR spills).
//
// R1 model: bus-saturated at ~110 MB effective read + 67 MB write = 28.1 us.
// Duplicate (other-half) reads only PARTIALLY L2-absorbed because the pair
// reads the batch in ANTI-correlated order: half-0 walks rows 0->1023,
// half-1 walks 512->1023 then 0->511. A line's two touches are ~7 us apart;
// 32 blocks/XCD stream ~8 MB through the 4 MB L2 in that window -> evicted.
// Fix: BOTH blocks traverse rows 0->1023 (half-1 reads the other half
// first, stashes own rows in the second loop). Pair touches now separated
// only by CU skew -> L2 hit / in-flight merge on the shared XCD.
// Prediction: FETCH ~67-75 MB, kernel ~23-24 us, total ~108-109.

#define NBATCH 128        // A*B
#define NROW   1024       // N == M
#define KDIM   64
#define ELEMS_PER_TENSOR (128ull * 1024ull * 64ull)  // 8388608

typedef float floatx4 __attribute__((ext_vector_type(4)));  // for nontemporal builtin

__global__ __launch_bounds__(1024)
void fused_sameorder_kernel(const float* __restrict__ u,
                            const float* __restrict__ v,
                            float* __restrict__ out) {
    const int bid   = blockIdx.x;        // 0..255 (1 block/CU)
    // Same-XCD pair swizzle: HW places block bid on XCD (bid & 7); pair
    // blocks (batch, half 0/1) are bids (i, i+8) -> same XCD -> shared L2.
    const int xcd   = bid & 7;
    const int slot  = bid >> 3;          // 0..31
    const int batch = xcd * 16 + (slot >> 1);  // 0..127
    const int half  = slot & 1;          // own rows: [half*512, half*512+512)
    const int tid   = threadIdx.x;       // 0..1023
    const int k4    = tid & 15;          // float4 column group (16 x 4 = 64 cols)
    const int rg    = tid >> 4;          // 0..63 row group
    const int wave  = tid >> 6;          // 0..15

    const size_t boff = (size_t)batch * NROW * KDIM;
    const float4* ub = (const float4*)(u + boff);
    const float4* vb = (const float4*)(v + boff);
    float* ou = out + boff;
    float* ov = out + ELEMS_PER_TENSOR + boff;

    // ---- Phase A: BOTH halves traverse rows 0..1023 in the same order -----
    // Row for global group gi is rg + 64*gi; gi 0..7 = lower half, 8..15 =
    // upper half. Own rows -> ur/vr registers; all rows -> colsum partials.
    float4 ur[8], vr[8];
    float4 su = make_float4(0.f, 0.f, 0.f, 0.f);
    float4 sv = make_float4(0.f, 0.f, 0.f, 0.f);

    if (half == 0) {
        #pragma unroll
        for (int i = 0; i < 8; ++i) {     // rows 0..511: own, stash
            size_t io = (size_t)(rg + 64 * i) * 16 + k4;  // wave: 4 rows x 1KB
            ur[i] = ub[io];
            vr[i] = vb[io];
            su.x += ur[i].x; su.y += ur[i].y; su.z += ur[i].z; su.w += ur[i].w;
            sv.x += vr[i].x; sv.y += vr[i].y; sv.z += vr[i].z; sv.w += vr[i].w;
        }
        #pragma unroll
        for (int i = 8; i < 16; ++i) {    // rows 512..1023: other, accum only
            size_t io = (size_t)(rg + 64 * i) * 16 + k4;
            float4 a = ub[io];
            float4 b = vb[io];
            su.x += a.x; su.y += a.y; su.z += a.z; su.w += a.w;
            sv.x += b.x; sv.y += b.y; sv.z += b.z; sv.w += b.w;
        }
    } else {
        #pragma unroll
        for (int i = 0; i < 8; ++i) {     // rows 0..511: other, accum only
            size_t io = (size_t)(rg + 64 * i) * 16 + k4;
            float4 a = ub[io];
            float4 b = vb[io];
            su.x += a.x; su.y += a.y; su.z += a.z; su.w += a.w;
            sv.x += b.x; sv.y += b.y; sv.z += b.z; sv.w += b.w;
        }
        #pragma unroll
        for (int i = 0; i < 8; ++i) {     // rows 512..1023: own, stash
            size_t io = (size_t)(rg + 64 * (i + 8)) * 16 + k4;
            ur[i] = ub[io];
            vr[i] = vb[io];
            su.x += ur[i].x; su.y += ur[i].y; su.z += ur[i].z; su.w += ur[i].w;
            sv.x += vr[i].x; sv.y += vr[i].y; sv.z += vr[i].z; sv.w += vr[i].w;
        }
    }

    // ---- Reduce: shfl across the 4 row-groups within each wave ------------
    su.x += __shfl_xor(su.x, 16); su.y += __shfl_xor(su.y, 16);
    su.z += __shfl_xor(su.z, 16); su.w += __shfl_xor(su.w, 16);
    su.x += __shfl_xor(su.x, 32); su.y += __shfl_xor(su.y, 32);
    su.z += __shfl_xor(su.z, 32); su.w += __shfl_xor(su.w, 32);
    sv.x += __shfl_xor(sv.x, 16); sv.y += __shfl_xor(sv.y, 16);
    sv.z += __shfl_xor(sv.z, 16); sv.w += __shfl_xor(sv.w, 16);
    sv.x += __shfl_xor(sv.x, 32); sv.y += __shfl_xor(sv.y, 32);
    sv.z += __shfl_xor(sv.z, 32); sv.w += __shfl_xor(sv.w, 32);

    __shared__ float4 red_u[16][16];   // [wave][k4]
    __shared__ float4 red_v[16][16];
    if ((tid & 63) < 16) {             // lanes 0..15 hold k4 = lane
        red_u[wave][k4] = su;
        red_v[wave][k4] = sv;
    }
    __syncthreads();                   // the ONLY barrier

    // all-thread self-reduce; same-k4 threads read same address (broadcast)
    float4 us = make_float4(0.f, 0.f, 0.f, 0.f);  // u colsum (masks v rows)
    float4 vs = make_float4(0.f, 0.f, 0.f, 0.f);  // v colsum (masks u rows)
    #pragma unroll
    for (int w = 0; w < 16; ++w) {
        float4 a = red_u[w][k4];
        float4 b = red_v[w][k4];
        us.x += a.x; us.y += a.y; us.z += a.z; us.w += a.w;
        vs.x += b.x; vs.y += b.y; vs.z += b.z; vs.w += b.w;
    }

    // ---- Phase B: mask own half from registers, streaming NT stores -------
    const int r_own0 = half * 512 + rg;
    #pragma unroll
    for (int i = 0; i < 8; ++i) {
        size_t io = (size_t)(r_own0 + 64 * i) * 16 + k4;

        float pu = ur[i].x * vs.x + ur[i].y * vs.y + ur[i].z * vs.z + ur[i].w * vs.w;
        pu += __shfl_xor(pu, 1);
        pu += __shfl_xor(pu, 2);
        pu += __shfl_xor(pu, 4);
        pu += __shfl_xor(pu, 8);       // full 64-col dot across the 16 k4 lanes
        float mu = (pu > 0.f) ? 1.f : 0.f;
        floatx4 outu = { ur[i].x * mu, ur[i].y * mu, ur[i].z * mu, ur[i].w * mu };
        __builtin_nontemporal_store(outu, (floatx4*)(ou + io * 4));

        float pv = vr[i].x * us.x + vr[i].y * us.y + vr[i].z * us.z + vr[i].w * us.w;
        pv += __shfl_xor(pv, 1);
        pv += __shfl_xor(pv, 2);
        pv += __shfl_xor(pv, 4);
        pv += __shfl_xor(pv, 8);
        float mv = (pv > 0.f) ? 1.f : 0.f;
        floatx4 outv = { vr[i].x * mv, vr[i].y * mv, vr[i].z * mv, vr[i].w * mv };
        __builtin_nontemporal_store(outv, (floatx4*)(ov + io * 4));
    }
}

extern "C" void kernel_launch(void* const* d_in, const int* in_sizes, int n_in,
                              void* d_out, int out_size, void* d_ws, size_t ws_size,
                              hipStream_t stream) {
    const float* u = (const float*)d_in[0];
    const float* v = (const float*)d_in[1];
    float* out = (float*)d_out;

    fused_sameorder_kernel<<<dim3(256), dim3(1024), 0, stream>>>(u, v, out);
}